// Round 2
// baseline (63.045 us; speedup 1.0000x reference)
//
#include <hip/hip_runtime.h>

#define T 512
#define CNT_OFF (96*1024)

__device__ __forceinline__ float wave_sum_all(float v){
    #pragma unroll
    for (int off = 1; off < 64; off <<= 1) v += __shfl_xor(v, off, 64);
    return v;
}

// One fused kernel. Blocks 0..13: stage1 (i,c,s MLPs) -> h[14][17][100] in ws.
// Blocks 14..217: stage2 per (f,b) task; f<10 spin on device-scope counter
// until all 14 stage1 blocks release, then run m/n -> t -> k -> p chain.
// 218 blocks <= 256 CUs, 114KB LDS -> 1 block/CU, all co-resident (no deadlock).
__global__ __launch_bounds__(T) void k_fused(
    const float* __restrict__ x,
    const float* __restrict__ iW1, const float* __restrict__ ib1,
    const float* __restrict__ ig,  const float* __restrict__ iB,
    const float* __restrict__ iW2, const float* __restrict__ ib2,
    const float* __restrict__ cW1, const float* __restrict__ cb1,
    const float* __restrict__ cg,  const float* __restrict__ cB,
    const float* __restrict__ cW2, const float* __restrict__ cb2,
    const float* __restrict__ sW1, const float* __restrict__ sb1,
    const float* __restrict__ sg,  const float* __restrict__ sB,
    const float* __restrict__ sW2, const float* __restrict__ sb2,
    const float* __restrict__ mW1, const float* __restrict__ mb1,
    const float* __restrict__ mg,  const float* __restrict__ mB,
    const float* __restrict__ mW2, const float* __restrict__ mb2,
    const float* __restrict__ nW1, const float* __restrict__ nb1,
    const float* __restrict__ ng,  const float* __restrict__ nB,
    const float* __restrict__ nW2, const float* __restrict__ nb2,
    const float* __restrict__ tW1, const float* __restrict__ tb1,
    const float* __restrict__ tg,  const float* __restrict__ tB,
    const float* __restrict__ tW2, const float* __restrict__ tb2,
    const float* __restrict__ kW1, const float* __restrict__ kb1,
    const float* __restrict__ kg,  const float* __restrict__ kB,
    const float* __restrict__ kW2, const float* __restrict__ kb2,
    const float* __restrict__ pW1, const float* __restrict__ pb1,
    const float* __restrict__ pg,  const float* __restrict__ pB,
    const float* __restrict__ pW2, const float* __restrict__ pb2,
    float* __restrict__ h_ws, unsigned int* __restrict__ cnt,
    float* __restrict__ out)
{
    const int bid = blockIdx.x;
    const int t = threadIdx.x;

    if (bid < 14) {
        // ---------------- stage1: per-a slice ----------------
        __shared__ float u[170][20];       // stage-i hidden, activated
        __shared__ float h1[17][10][100];  // stage-i output
        __shared__ float h2[17][100];      // stage-c output
        __shared__ float spre[100][34];    // stage-s hidden
        const int a = bid;

        // Phase A: i first linear + LN(20) + relu, one thread per row
        if (t < 170) {
            const float* xr = x + (a*170 + t)*3;
            float x0 = xr[0], x1 = xr[1], x2 = xr[2];
            float pre[20];
            float mu = 0.f;
            #pragma unroll
            for (int j = 0; j < 20; ++j) {
                float v = ib1[j] + x0*iW1[j] + x1*iW1[20+j] + x2*iW1[40+j];
                pre[j] = v; mu += v;
            }
            mu *= 0.05f;
            float var = 0.f;
            #pragma unroll
            for (int j = 0; j < 20; ++j) { float d = pre[j]-mu; var = fmaf(d,d,var); }
            float inv = rsqrtf(var*0.05f + 1e-5f);
            #pragma unroll
            for (int j = 0; j < 20; ++j) {
                float v = (pre[j]-mu)*inv*ig[j] + iB[j];
                u[t][j] = v > 0.f ? v : 0.f;
            }
        }
        __syncthreads();

        // Phase B: i second linear. thread = (rg, d): weights in registers,
        // u rows as float4 LDS reads. 170 = 5*34 rows.
        if (t < 500) {
            int d = t % 100, rg = t / 100;
            float w[20];
            #pragma unroll
            for (int j = 0; j < 20; ++j) w[j] = iW2[j*100+d];
            float bias = ib2[d];
            #pragma unroll 2
            for (int r = rg*34; r < rg*34+34; ++r) {
                const float4* ur = (const float4*)u[r];
                float4 u0=ur[0], u1=ur[1], u2=ur[2], u3=ur[3], u4=ur[4];
                float acc = bias;
                acc=fmaf(u0.x,w[0],acc);  acc=fmaf(u0.y,w[1],acc);
                acc=fmaf(u0.z,w[2],acc);  acc=fmaf(u0.w,w[3],acc);
                acc=fmaf(u1.x,w[4],acc);  acc=fmaf(u1.y,w[5],acc);
                acc=fmaf(u1.z,w[6],acc);  acc=fmaf(u1.w,w[7],acc);
                acc=fmaf(u2.x,w[8],acc);  acc=fmaf(u2.y,w[9],acc);
                acc=fmaf(u2.z,w[10],acc); acc=fmaf(u2.w,w[11],acc);
                acc=fmaf(u3.x,w[12],acc); acc=fmaf(u3.y,w[13],acc);
                acc=fmaf(u3.z,w[14],acc); acc=fmaf(u3.w,w[15],acc);
                acc=fmaf(u4.x,w[16],acc); acc=fmaf(u4.y,w[17],acc);
                acc=fmaf(u4.z,w[18],acc); acc=fmaf(u4.w,w[19],acc);
                ((float*)h1)[r*100+d] = acc;
            }
        }
        __syncthreads();

        // Phase C: stage c (10->8->1) per (b,d)
        for (int o = t; o < 1700; o += T) {
            int b = o / 100, d = o - 100*b;
            float w[8];
            #pragma unroll
            for (int j = 0; j < 8; ++j) w[j] = cb1[j];
            #pragma unroll
            for (int c = 0; c < 10; ++c) {
                float v = h1[b][c][d];
                #pragma unroll
                for (int j = 0; j < 8; ++j) w[j] = fmaf(v, cW1[c*8+j], w[j]);
            }
            float mu = 0.f;
            #pragma unroll
            for (int j = 0; j < 8; ++j) mu += w[j];
            mu *= 0.125f;
            float var = 0.f;
            #pragma unroll
            for (int j = 0; j < 8; ++j) { float d2 = w[j]-mu; var = fmaf(d2,d2,var); }
            float inv = rsqrtf(var*0.125f + 1e-5f);
            float acc = cb2[0];
            #pragma unroll
            for (int j = 0; j < 8; ++j) {
                float v = (w[j]-mu)*inv*cg[j] + cB[j];
                v = v > 0.f ? v : 0.f;
                acc = fmaf(v, cW2[j], acc);
            }
            h2[b][d] = acc;
        }
        __syncthreads();

        // Phase D: s first linear (d,j): 100x34, 17 MACs
        for (int o = t; o < 3400; o += T) {
            int d = o / 34, j = o - 34*d;
            float acc = sb1[j];
            #pragma unroll
            for (int b = 0; b < 17; ++b) acc = fmaf(h2[b][d], sW1[b*34+j], acc);
            spre[d][j] = acc;
        }
        __syncthreads();

        // Phase E: LN(34)+relu per d-row
        if (t < 100) {
            float mu = 0.f;
            #pragma unroll
            for (int j = 0; j < 34; ++j) mu += spre[t][j];
            mu *= (1.f/34.f);
            float var = 0.f;
            #pragma unroll
            for (int j = 0; j < 34; ++j) { float d = spre[t][j]-mu; var = fmaf(d,d,var); }
            float inv = rsqrtf(var*(1.f/34.f) + 1e-5f);
            #pragma unroll
            for (int j = 0; j < 34; ++j) {
                float v = (spre[t][j]-mu)*inv*sg[j] + sB[j];
                spre[t][j] = v > 0.f ? v : 0.f;
            }
        }
        __syncthreads();

        // Phase F: s second linear, transposed write h[a][b2][d]
        for (int o = t; o < 1700; o += T) {
            int d = o / 17, b2 = o - 17*d;
            float acc = sb2[b2];
            #pragma unroll
            for (int j = 0; j < 34; ++j) acc = fmaf(spre[d][j], sW2[j*17+b2], acc);
            h_ws[a*1700 + b2*100 + d] = acc;
        }
        __syncthreads();
        if (t == 0) {
            __threadfence();
            __hip_atomic_fetch_add(cnt, 1u, __ATOMIC_RELEASE, __HIP_MEMORY_SCOPE_AGENT);
        }
        return;
    }

    // ---------------- stage2: per (f,b) task ----------------
    const int task = bid - 14;
    const int f = task / 17, b = task % 17;
    const bool full = (f < 10);

    __shared__ float inrow[5][100];     // dA, hA, dC, hD, hE
    __shared__ float mnpart[4][2][20];
    __shared__ float hid4[4][20];
    __shared__ float v4[4][100];        // m(dA), n(hA), m(dC), n(hD)
    __shared__ float tpart[2][4][20];
    __shared__ float hidT[2][20];
    __shared__ float tv[2][100];        // pf, nf
    __shared__ float kin[300];
    __shared__ float kpart[4][100];
    __shared__ float khid[100];
    __shared__ float k2part[4][100];
    __shared__ float comb[100];
    __shared__ float ppart[4][30];
    __shared__ float pact[30];
    __shared__ float red[8];

    if (full) {
        // wait for stage1 (device-scope acquire)
        if (t == 0) {
            while (__hip_atomic_load(cnt, __ATOMIC_ACQUIRE, __HIP_MEMORY_SCOPE_AGENT) < 14u) {
                __builtin_amdgcn_s_sleep(2);
            }
        }
        __syncthreads();

        if (t < 100) {
            const float* hb = h_ws + b*100 + t;
            float h0  = hb[(f  )*1700];
            float h1v = hb[(f+1)*1700];
            float h2v = hb[(f+2)*1700];
            float h3v = hb[(f+3)*1700];
            float h4v = hb[(f+4)*1700];
            inrow[0][t] = h1v - h0;
            inrow[1][t] = h1v;
            inrow[2][t] = h4v - h3v;
            inrow[3][t] = h3v;
            inrow[4][t] = h2v;
        }
        __syncthreads();

        // m/n lin1, split-K x2: 160 threads
        if (t < 160) {
            int which = t / 40, rem = t % 40, half = rem / 20, jj = rem % 20;
            bool is_m = (which == 0) || (which == 2);
            const float* W1 = is_m ? mW1 : nW1;
            const float* in = inrow[which];
            int e0 = half*50;
            float a0 = 0.f, a1 = 0.f;
            #pragma unroll
            for (int e = 0; e < 50; e += 2) {
                a0 = fmaf(in[e0+e],   W1[(e0+e)*20+jj],   a0);
                a1 = fmaf(in[e0+e+1], W1[(e0+e+1)*20+jj], a1);
            }
            mnpart[which][half][jj] = a0 + a1;
        }
        __syncthreads();

        // combine + LN(20)+relu, one wave per row (waves 0..3)
        {
            int w = t >> 6, lane = t & 63;
            bool act = (w < 4) && (lane < 20);
            bool is_m = (w == 0) || (w == 2);
            float v = 0.f;
            if (act) {
                const float* B1 = is_m ? mb1 : nb1;
                v = B1[lane] + mnpart[w][0][lane] + mnpart[w][1][lane];
            }
            float mu = wave_sum_all(v) * 0.05f;
            float dd = act ? (v-mu) : 0.f;
            float inv = rsqrtf(wave_sum_all(dd*dd)*0.05f + 1e-5f);
            if (act) {
                const float* g  = is_m ? mg : ng;
                const float* Bv = is_m ? mB : nB;
                float r = (v-mu)*inv*g[lane] + Bv[lane];
                hid4[w][lane] = r > 0.f ? r : 0.f;
            }
        }
        __syncthreads();

        // m/n lin2: 400 outputs, 20 MACs each
        if (t < 400) {
            int which = t / 100, d = t % 100;
            bool is_m = (which == 0) || (which == 2);
            const float* W2 = is_m ? mW2 : nW2;
            const float* B2 = is_m ? mb2 : nb2;
            float acc = B2[d];
            #pragma unroll
            for (int j = 0; j < 20; ++j) acc = fmaf(hid4[which][j], W2[j*100+d], acc);
            v4[which][d] = acc;
        }
        __syncthreads();

        // t lin1, split-K x4: 160 threads. concat = [n_out, m_out]
        if (t < 160) {
            int jj = t % 20, q8 = t / 20;
            int which = q8 >> 2, q = q8 & 3;
            const float* inA = which ? v4[3] : v4[1];
            const float* inB = which ? v4[2] : v4[0];
            int e0 = q*50;
            const float* in = (q < 2) ? inA : inB;
            int inoff = (q < 2) ? e0 : e0 - 100;
            float a0 = 0.f, a1 = 0.f;
            #pragma unroll
            for (int e = 0; e < 50; e += 2) {
                a0 = fmaf(in[inoff+e],   tW1[(e0+e)*20+jj],   a0);
                a1 = fmaf(in[inoff+e+1], tW1[(e0+e+1)*20+jj], a1);
            }
            tpart[which][q][jj] = a0 + a1;
        }
        __syncthreads();

        // combine + LN(20)+relu, waves 0..1
        {
            int w = t >> 6, lane = t & 63;
            bool act = (w < 2) && (lane < 20);
            float v = 0.f;
            if (act)
                v = tb1[lane] + tpart[w][0][lane] + tpart[w][1][lane]
                              + tpart[w][2][lane] + tpart[w][3][lane];
            float mu = wave_sum_all(v) * 0.05f;
            float dd = act ? (v-mu) : 0.f;
            float inv = rsqrtf(wave_sum_all(dd*dd)*0.05f + 1e-5f);
            if (act) {
                float r = (v-mu)*inv*tg[lane] + tB[lane];
                hidT[w][lane] = r > 0.f ? r : 0.f;
            }
        }
        __syncthreads();

        // t lin2: 200 outputs x 20 MACs
        if (t < 200) {
            int which = t / 100, d = t % 100;
            float acc = tb2[d];
            #pragma unroll
            for (int j = 0; j < 20; ++j) acc = fmaf(hidT[which][j], tW2[j*100+d], acc);
            tv[which][d] = acc;
        }
        __syncthreads();

        // kin = concat [pf, hE, nf]
        if (t < 300)
            kin[t] = (t < 100) ? tv[0][t] : (t < 200 ? inrow[4][t-100] : tv[1][t-200]);
        __syncthreads();

        // k lin1, split-K x4: 400 threads, 75 MACs each
        if (t < 400) {
            int o = t % 100, q = t / 100;
            int e0 = q*75;
            float a0=0.f, a1=0.f, a2=0.f;
            #pragma unroll
            for (int e = 0; e < 75; e += 3) {
                a0 = fmaf(kin[e0+e],   kW1[(e0+e)*100+o],   a0);
                a1 = fmaf(kin[e0+e+1], kW1[(e0+e+1)*100+o], a1);
                a2 = fmaf(kin[e0+e+2], kW1[(e0+e+2)*100+o], a2);
            }
            kpart[q][o] = a0 + a1 + a2;
        }
        __syncthreads();

        // LN(100) block-wide
        {
            float kv = 0.f;
            if (t < 100)
                kv = kb1[t] + kpart[0][t] + kpart[1][t] + kpart[2][t] + kpart[3][t];
            float s = wave_sum_all((t < 100) ? kv : 0.f);
            if ((t & 63) == 0) red[t >> 6] = s;
            __syncthreads();
            float mu = (red[0]+red[1]+red[2]+red[3]+red[4]+red[5]+red[6]+red[7]) * 0.01f;
            __syncthreads();
            float dd = (t < 100) ? (kv-mu) : 0.f;
            float s2 = wave_sum_all(dd*dd);
            if ((t & 63) == 0) red[t >> 6] = s2;
            __syncthreads();
            float var = (red[0]+red[1]+red[2]+red[3]+red[4]+red[5]+red[6]+red[7]) * 0.01f;
            float inv = rsqrtf(var + 1e-5f);
            if (t < 100) {
                float r = (kv-mu)*inv*kg[t] + kB[t];
                khid[t] = r > 0.f ? r : 0.f;
            }
        }
        __syncthreads();

        // k lin2, split-K x4: 400 threads, 25 MACs each
        if (t < 400) {
            int o = t % 100, q = t / 100, j0 = q*25;
            float a0 = 0.f;
            #pragma unroll
            for (int j = 0; j < 25; ++j)
                a0 = fmaf(khid[j0+j], kW2[(j0+j)*100+o], a0);
            k2part[q][o] = a0;
        }
        __syncthreads();
        if (t < 100)
            comb[t] = kb2[t] + k2part[0][t] + k2part[1][t] + k2part[2][t] + k2part[3][t];
        __syncthreads();
    } else {
        if (t < 100) comb[t] = 0.f;
        __syncthreads();
    }

    // p stage: 100 -> 30 (LN) -> 3. lin1 split-K x4: 120 threads.
    if (t < 120) {
        int o = t % 30, q = t / 30, e0 = q*25;
        float a0 = 0.f;
        #pragma unroll
        for (int e = 0; e < 25; ++e)
            a0 = fmaf(comb[e0+e], pW1[(e0+e)*30+o], a0);
        ppart[q][o] = a0;
    }
    __syncthreads();
    // LN(30) on wave 0
    if (t < 64) {
        float v = 0.f;
        if (t < 30) v = pb1[t] + ppart[0][t] + ppart[1][t] + ppart[2][t] + ppart[3][t];
        float mu = wave_sum_all(v) * (1.f/30.f);
        float dd = (t < 30) ? (v-mu) : 0.f;
        float inv = rsqrtf(wave_sum_all(dd*dd)*(1.f/30.f) + 1e-5f);
        if (t < 30) {
            float r = (v-mu)*inv*pg[t] + pB[t];
            pact[t] = r > 0.f ? r : 0.f;
        }
    }
    __syncthreads();
    if (t < 3) {
        float acc = pb2[t];
        #pragma unroll
        for (int j = 0; j < 30; ++j) acc = fmaf(pact[j], pW2[j*3+t], acc);
        out[(f*17 + b)*3 + t] = acc;
    }
}

extern "C" void kernel_launch(void* const* d_in, const int* in_sizes, int n_in,
                              void* d_out, int out_size, void* d_ws, size_t ws_size,
                              hipStream_t stream) {
    const float* x = (const float*)d_in[0];
    float* h = (float*)d_ws;                                   // 23800 floats
    unsigned int* cnt = (unsigned int*)((char*)d_ws + CNT_OFF);
    hipMemsetAsync(cnt, 0, sizeof(unsigned int), stream);      // per-call barrier reset
    #define P(i) ((const float*)d_in[i])
    k_fused<<<218, T, 0, stream>>>(x,
        P(1), P(2), P(3), P(4), P(5), P(6),
        P(7), P(8), P(9), P(10), P(11), P(12),
        P(13), P(14), P(15), P(16), P(17), P(18),
        P(19), P(20), P(21), P(22), P(23), P(24),
        P(25), P(26), P(27), P(28), P(29), P(30),
        P(31), P(32), P(33), P(34), P(35), P(36),
        P(37), P(38), P(39), P(40), P(41), P(42),
        P(43), P(44), P(45), P(46), P(47), P(48),
        h, cnt, (float*)d_out);
    #undef P
}

// Round 3
// 53.687 us; speedup vs baseline: 1.1743x; 1.1743x over previous
//
#include <hip/hip_runtime.h>

#define T 256
#define H2_OFF   24576          // float offset of h2ws in ws (byte 98304)
#define CNT_BYTE 200704         // byte offset of counters (64B aligned)

__device__ __forceinline__ float wave_sum_all(float v){
    #pragma unroll
    for (int off = 1; off < 64; off <<= 1) v += __shfl_xor(v, off, 64);
    return v;
}

// Fused kernel, 238 blocks x 256 threads, spin barriers with RELAXED polling.
// ROLE1 (all 238 blocks): per-(a,b) stage i (3->20->100) + stage c (10->8->1)
//   -> h2ws[a][b][0..99]; release cntA[a] (17 producers, 1 poller each).
// ROLE2 (blocks 0..13): wait cntA[a]==17; stage s (17->34->17) -> h[a][b2][d];
//   release cntH.
// ROLE3 (blocks 14..217): task (f,b); f<10 wait cntH==14 then m/n->t->k->p.
__global__ __launch_bounds__(T) void k_fused(
    const float* __restrict__ x,
    const float* __restrict__ iW1, const float* __restrict__ ib1,
    const float* __restrict__ ig,  const float* __restrict__ iB,
    const float* __restrict__ iW2, const float* __restrict__ ib2,
    const float* __restrict__ cW1, const float* __restrict__ cb1,
    const float* __restrict__ cg,  const float* __restrict__ cB,
    const float* __restrict__ cW2, const float* __restrict__ cb2,
    const float* __restrict__ sW1, const float* __restrict__ sb1,
    const float* __restrict__ sg,  const float* __restrict__ sB,
    const float* __restrict__ sW2, const float* __restrict__ sb2,
    const float* __restrict__ mW1, const float* __restrict__ mb1,
    const float* __restrict__ mg,  const float* __restrict__ mB,
    const float* __restrict__ mW2, const float* __restrict__ mb2,
    const float* __restrict__ nW1, const float* __restrict__ nb1,
    const float* __restrict__ ng,  const float* __restrict__ nB,
    const float* __restrict__ nW2, const float* __restrict__ nb2,
    const float* __restrict__ tW1, const float* __restrict__ tb1,
    const float* __restrict__ tg,  const float* __restrict__ tB,
    const float* __restrict__ tW2, const float* __restrict__ tb2,
    const float* __restrict__ kW1, const float* __restrict__ kb1,
    const float* __restrict__ kg,  const float* __restrict__ kB,
    const float* __restrict__ kW2, const float* __restrict__ kb2,
    const float* __restrict__ pW1, const float* __restrict__ pb1,
    const float* __restrict__ pg,  const float* __restrict__ pB,
    const float* __restrict__ pW2, const float* __restrict__ pb2,
    float* __restrict__ h_ws, float* __restrict__ h2ws,
    unsigned int* __restrict__ cntA, unsigned int* __restrict__ cntH,
    float* __restrict__ out)
{
    const int bid = blockIdx.x;
    const int t = threadIdx.x;

    // role1 LDS
    __shared__ float u10[10][20];
    __shared__ float h1s[10][100];
    // role2 LDS
    __shared__ float h2s[17][100];
    __shared__ float spre[100][34];
    // role3 LDS
    __shared__ float inrow[5][100];
    __shared__ float mnpart[4][2][20];
    __shared__ float hid4[4][20];
    __shared__ float v4[4][100];
    __shared__ float tpart[2][4][20];
    __shared__ float hidT[2][20];
    __shared__ float tv[2][100];
    __shared__ float kin[300];
    __shared__ float kpart[2][100];
    __shared__ float khid[100];
    __shared__ float comb[100];
    __shared__ float ppart[4][30];
    __shared__ float pact[30];
    __shared__ float red[4];

    // ================= ROLE 1: stage i + c for (a,b) =================
    {
        const int a = bid / 17, b = bid % 17;

        // i lin1: t<200 -> (c,j)
        if (t < 200) {
            int c = t / 20, j = t % 20;
            const float* xr = x + ((a*17 + b)*10 + c)*3;
            u10[c][j] = ib1[j] + xr[0]*iW1[j] + xr[1]*iW1[20+j] + xr[2]*iW1[40+j];
        }
        __syncthreads();
        // LN(20)+relu per row c, serial (tiny)
        if (t < 10) {
            float mu = 0.f;
            #pragma unroll
            for (int j = 0; j < 20; ++j) mu += u10[t][j];
            mu *= 0.05f;
            float var = 0.f;
            #pragma unroll
            for (int j = 0; j < 20; ++j) { float d = u10[t][j]-mu; var = fmaf(d,d,var); }
            float inv = rsqrtf(var*0.05f + 1e-5f);
            #pragma unroll
            for (int j = 0; j < 20; ++j) {
                float v = (u10[t][j]-mu)*inv*ig[j] + iB[j];
                u10[t][j] = v > 0.f ? v : 0.f;
            }
        }
        __syncthreads();
        // i lin2: 1000 outputs x 20 MACs
        for (int o = t; o < 1000; o += T) {
            int c = o / 100, d = o - 100*c;
            float acc = ib2[d];
            #pragma unroll
            for (int j = 0; j < 20; ++j) acc = fmaf(u10[c][j], iW2[j*100+d], acc);
            h1s[c][d] = acc;
        }
        __syncthreads();
        // stage c per d
        if (t < 100) {
            float w[8];
            #pragma unroll
            for (int j = 0; j < 8; ++j) w[j] = cb1[j];
            #pragma unroll
            for (int c = 0; c < 10; ++c) {
                float v = h1s[c][t];
                #pragma unroll
                for (int j = 0; j < 8; ++j) w[j] = fmaf(v, cW1[c*8+j], w[j]);
            }
            float mu = 0.f;
            #pragma unroll
            for (int j = 0; j < 8; ++j) mu += w[j];
            mu *= 0.125f;
            float var = 0.f;
            #pragma unroll
            for (int j = 0; j < 8; ++j) { float d2 = w[j]-mu; var = fmaf(d2,d2,var); }
            float inv = rsqrtf(var*0.125f + 1e-5f);
            float acc = cb2[0];
            #pragma unroll
            for (int j = 0; j < 8; ++j) {
                float v = (w[j]-mu)*inv*cg[j] + cB[j];
                v = v > 0.f ? v : 0.f;
                acc = fmaf(v, cW2[j], acc);
            }
            h2ws[(a*17 + b)*100 + t] = acc;
        }
        __syncthreads();
        if (t == 0) {
            __threadfence();
            __hip_atomic_fetch_add(&cntA[a], 1u, __ATOMIC_RELEASE, __HIP_MEMORY_SCOPE_AGENT);
        }
    }

    // ================= ROLE 2: stage s for slice a = bid =================
    if (bid < 14) {
        const int a = bid;
        if (t == 0) {
            while (__hip_atomic_load(&cntA[a], __ATOMIC_RELAXED, __HIP_MEMORY_SCOPE_AGENT) < 17u)
                __builtin_amdgcn_s_sleep(2);
            (void)__hip_atomic_load(&cntA[a], __ATOMIC_ACQUIRE, __HIP_MEMORY_SCOPE_AGENT);
        }
        __syncthreads();
        for (int o = t; o < 1700; o += T) ((float*)h2s)[o] = h2ws[a*1700 + o];
        __syncthreads();
        // s lin1: 3400 outputs x 17 MACs
        for (int o = t; o < 3400; o += T) {
            int d = o / 34, j = o - 34*d;
            float acc = sb1[j];
            #pragma unroll
            for (int b = 0; b < 17; ++b) acc = fmaf(h2s[b][d], sW1[b*34+j], acc);
            spre[d][j] = acc;
        }
        __syncthreads();
        // LN(34)+relu per d
        if (t < 100) {
            float mu = 0.f;
            #pragma unroll
            for (int j = 0; j < 34; ++j) mu += spre[t][j];
            mu *= (1.f/34.f);
            float var = 0.f;
            #pragma unroll
            for (int j = 0; j < 34; ++j) { float d = spre[t][j]-mu; var = fmaf(d,d,var); }
            float inv = rsqrtf(var*(1.f/34.f) + 1e-5f);
            #pragma unroll
            for (int j = 0; j < 34; ++j) {
                float v = (spre[t][j]-mu)*inv*sg[j] + sB[j];
                spre[t][j] = v > 0.f ? v : 0.f;
            }
        }
        __syncthreads();
        // s lin2, transposed write h[a][b2][d]
        for (int o = t; o < 1700; o += T) {
            int d = o / 17, b2 = o - 17*d;
            float acc = sb2[b2];
            #pragma unroll
            for (int j = 0; j < 34; ++j) acc = fmaf(spre[d][j], sW2[j*17+b2], acc);
            h_ws[a*1700 + b2*100 + d] = acc;
        }
        __syncthreads();
        if (t == 0) {
            __threadfence();
            __hip_atomic_fetch_add(cntH, 1u, __ATOMIC_RELEASE, __HIP_MEMORY_SCOPE_AGENT);
        }
        return;
    }

    // ================= ROLE 3: stage2 task (f,b) =================
    const int task = bid - 14;
    const int f = task / 17, b = task % 17;
    const bool full = (f < 10);

    if (full) {
        if (t == 0) {
            while (__hip_atomic_load(cntH, __ATOMIC_RELAXED, __HIP_MEMORY_SCOPE_AGENT) < 14u)
                __builtin_amdgcn_s_sleep(16);
            (void)__hip_atomic_load(cntH, __ATOMIC_ACQUIRE, __HIP_MEMORY_SCOPE_AGENT);
        }
        __syncthreads();

        if (t < 100) {
            const float* hb = h_ws + b*100 + t;
            float h0  = hb[(f  )*1700];
            float h1v = hb[(f+1)*1700];
            float h2v = hb[(f+2)*1700];
            float h3v = hb[(f+3)*1700];
            float h4v = hb[(f+4)*1700];
            inrow[0][t] = h1v - h0;
            inrow[1][t] = h1v;
            inrow[2][t] = h4v - h3v;
            inrow[3][t] = h3v;
            inrow[4][t] = h2v;
        }
        __syncthreads();

        // m/n lin1, split-K x2
        if (t < 160) {
            int which = t / 40, rem = t % 40, half = rem / 20, jj = rem % 20;
            bool is_m = (which == 0) || (which == 2);
            const float* W1 = is_m ? mW1 : nW1;
            const float* in = inrow[which];
            int e0 = half*50;
            float a0 = 0.f, a1 = 0.f;
            #pragma unroll
            for (int e = 0; e < 50; e += 2) {
                a0 = fmaf(in[e0+e],   W1[(e0+e)*20+jj],   a0);
                a1 = fmaf(in[e0+e+1], W1[(e0+e+1)*20+jj], a1);
            }
            mnpart[which][half][jj] = a0 + a1;
        }
        __syncthreads();

        // combine + LN(20)+relu, one wave per row (4 waves)
        {
            int w = t >> 6, lane = t & 63;
            bool act = (lane < 20);
            bool is_m = (w == 0) || (w == 2);
            float v = 0.f;
            if (act) {
                const float* B1 = is_m ? mb1 : nb1;
                v = B1[lane] + mnpart[w][0][lane] + mnpart[w][1][lane];
            }
            float mu = wave_sum_all(v) * 0.05f;
            float dd = act ? (v-mu) : 0.f;
            float inv = rsqrtf(wave_sum_all(dd*dd)*0.05f + 1e-5f);
            if (act) {
                const float* g  = is_m ? mg : ng;
                const float* Bv = is_m ? mB : nB;
                float r = (v-mu)*inv*g[lane] + Bv[lane];
                hid4[w][lane] = r > 0.f ? r : 0.f;
            }
        }
        __syncthreads();

        // m/n lin2: 400 outputs x 20 MACs
        for (int o = t; o < 400; o += T) {
            int which = o / 100, d = o % 100;
            bool is_m = (which == 0) || (which == 2);
            const float* W2 = is_m ? mW2 : nW2;
            const float* B2 = is_m ? mb2 : nb2;
            float acc = B2[d];
            #pragma unroll
            for (int j = 0; j < 20; ++j) acc = fmaf(hid4[which][j], W2[j*100+d], acc);
            v4[which][d] = acc;
        }
        __syncthreads();

        // t lin1, split-K x4. concat = [n_out, m_out]
        if (t < 160) {
            int jj = t % 20, q8 = t / 20;
            int which = q8 >> 2, q = q8 & 3;
            const float* inA = which ? v4[3] : v4[1];
            const float* inB = which ? v4[2] : v4[0];
            int e0 = q*50;
            const float* in = (q < 2) ? inA : inB;
            int inoff = (q < 2) ? e0 : e0 - 100;
            float a0 = 0.f, a1 = 0.f;
            #pragma unroll
            for (int e = 0; e < 50; e += 2) {
                a0 = fmaf(in[inoff+e],   tW1[(e0+e)*20+jj],   a0);
                a1 = fmaf(in[inoff+e+1], tW1[(e0+e+1)*20+jj], a1);
            }
            tpart[which][q][jj] = a0 + a1;
        }
        __syncthreads();

        // combine + LN(20)+relu, waves 0..1
        {
            int w = t >> 6, lane = t & 63;
            bool act = (w < 2) && (lane < 20);
            float v = 0.f;
            if (act)
                v = tb1[lane] + tpart[w][0][lane] + tpart[w][1][lane]
                              + tpart[w][2][lane] + tpart[w][3][lane];
            float mu = wave_sum_all(v) * 0.05f;
            float dd = act ? (v-mu) : 0.f;
            float inv = rsqrtf(wave_sum_all(dd*dd)*0.05f + 1e-5f);
            if (act) {
                float r = (v-mu)*inv*tg[lane] + tB[lane];
                hidT[w][lane] = r > 0.f ? r : 0.f;
            }
        }
        __syncthreads();

        // t lin2: 200 outputs x 20 MACs
        if (t < 200) {
            int which = t / 100, d = t % 100;
            float acc = tb2[d];
            #pragma unroll
            for (int j = 0; j < 20; ++j) acc = fmaf(hidT[which][j], tW2[j*100+d], acc);
            tv[which][d] = acc;
        }
        __syncthreads();

        // kin = concat [pf, hE, nf]
        for (int o = t; o < 300; o += T)
            kin[o] = (o < 100) ? tv[0][o] : (o < 200 ? inrow[4][o-100] : tv[1][o-200]);
        __syncthreads();

        // k lin1, split-K x2: 200 threads x 150 MACs
        if (t < 200) {
            int o = t % 100, q = t / 100, e0 = q*150;
            float a0=0.f, a1=0.f, a2=0.f;
            #pragma unroll
            for (int e = 0; e < 150; e += 3) {
                a0 = fmaf(kin[e0+e],   kW1[(e0+e)*100+o],   a0);
                a1 = fmaf(kin[e0+e+1], kW1[(e0+e+1)*100+o], a1);
                a2 = fmaf(kin[e0+e+2], kW1[(e0+e+2)*100+o], a2);
            }
            kpart[q][o] = a0 + a1 + a2;
        }
        __syncthreads();

        // LN(100) block-wide (4 waves)
        {
            float kv = 0.f;
            if (t < 100) kv = kb1[t] + kpart[0][t] + kpart[1][t];
            float s = wave_sum_all((t < 100) ? kv : 0.f);
            if ((t & 63) == 0) red[t >> 6] = s;
            __syncthreads();
            float mu = (red[0]+red[1]+red[2]+red[3]) * 0.01f;
            __syncthreads();
            float dd = (t < 100) ? (kv-mu) : 0.f;
            float s2 = wave_sum_all(dd*dd);
            if ((t & 63) == 0) red[t >> 6] = s2;
            __syncthreads();
            float inv = rsqrtf((red[0]+red[1]+red[2]+red[3])*0.01f + 1e-5f);
            if (t < 100) {
                float r = (kv-mu)*inv*kg[t] + kB[t];
                khid[t] = r > 0.f ? r : 0.f;
            }
        }
        __syncthreads();

        // k lin2: 100 outputs x 100 MACs
        if (t < 100) {
            float a0=0.f,a1=0.f,a2=0.f,a3=0.f;
            for (int j = 0; j < 100; j += 4) {
                a0 = fmaf(khid[j+0], kW2[(j+0)*100+t], a0);
                a1 = fmaf(khid[j+1], kW2[(j+1)*100+t], a1);
                a2 = fmaf(khid[j+2], kW2[(j+2)*100+t], a2);
                a3 = fmaf(khid[j+3], kW2[(j+3)*100+t], a3);
            }
            comb[t] = kb2[t] + ((a0+a1)+(a2+a3));
        }
        __syncthreads();
    } else {
        if (t < 100) comb[t] = 0.f;
        __syncthreads();
    }

    // p stage: 100 -> 30 (LN) -> 3, lin1 split-K x4
    if (t < 120) {
        int o = t % 30, q = t / 30, e0 = q*25;
        float a0 = 0.f;
        #pragma unroll
        for (int e = 0; e < 25; ++e)
            a0 = fmaf(comb[e0+e], pW1[(e0+e)*30+o], a0);
        ppart[q][o] = a0;
    }
    __syncthreads();
    if (t < 64) {
        float v = 0.f;
        if (t < 30) v = pb1[t] + ppart[0][t] + ppart[1][t] + ppart[2][t] + ppart[3][t];
        float mu = wave_sum_all(v) * (1.f/30.f);
        float dd = (t < 30) ? (v-mu) : 0.f;
        float inv = rsqrtf(wave_sum_all(dd*dd)*(1.f/30.f) + 1e-5f);
        if (t < 30) {
            float r = (v-mu)*inv*pg[t] + pB[t];
            pact[t] = r > 0.f ? r : 0.f;
        }
    }
    __syncthreads();
    if (t < 3) {
        float acc = pb2[t];
        #pragma unroll
        for (int j = 0; j < 30; ++j) acc = fmaf(pact[j], pW2[j*3+t], acc);
        out[(f*17 + b)*3 + t] = acc;
    }
}

extern "C" void kernel_launch(void* const* d_in, const int* in_sizes, int n_in,
                              void* d_out, int out_size, void* d_ws, size_t ws_size,
                              hipStream_t stream) {
    const float* x = (const float*)d_in[0];
    float* h   = (float*)d_ws;                    // [14][17][100]
    float* h2w = (float*)d_ws + H2_OFF;           // [14][17][100]
    unsigned int* cnt = (unsigned int*)((char*)d_ws + CNT_BYTE);
    hipMemsetAsync(cnt, 0, 64, stream);           // cntA[14] + cntH
    #define P(i) ((const float*)d_in[i])
    k_fused<<<238, T, 0, stream>>>(x,
        P(1), P(2), P(3), P(4), P(5), P(6),
        P(7), P(8), P(9), P(10), P(11), P(12),
        P(13), P(14), P(15), P(16), P(17), P(18),
        P(19), P(20), P(21), P(22), P(23), P(24),
        P(25), P(26), P(27), P(28), P(29), P(30),
        P(31), P(32), P(33), P(34), P(35), P(36),
        P(37), P(38), P(39), P(40), P(41), P(42),
        P(43), P(44), P(45), P(46), P(47), P(48),
        h, h2w, cnt, cnt + 14, (float*)d_out);
    #undef P
}

// Round 4
// 50.370 us; speedup vs baseline: 1.2516x; 1.0658x over previous
//
#include <hip/hip_runtime.h>

#define T 512
#define FLAG_BYTE 98304   // byte offset of flags in ws (128B-aligned)

__device__ __forceinline__ float wave_sum_all(float v){
    #pragma unroll
    for (int off = 1; off < 64; off <<= 1) v += __shfl_xor(v, off, 64);
    return v;
}

// 218 blocks x 512 threads.
// Blocks 0..13: full stage1 slice a (i: 3->20->100, c: 10->8->1, s: 17->34->17)
//   entirely in LDS -> h[a][b2][d] in ws; then fence(release)+store flag[a].
// Blocks 14..217: task (f,b). f<10: wave0 polls the 14 padded flags (relaxed,
//   read-only), fence(acquire), then m/n -> t -> k -> p chain.
__global__ __launch_bounds__(T) void k_fused(
    const float* __restrict__ x,
    const float* __restrict__ iW1, const float* __restrict__ ib1,
    const float* __restrict__ ig,  const float* __restrict__ iB,
    const float* __restrict__ iW2, const float* __restrict__ ib2,
    const float* __restrict__ cW1, const float* __restrict__ cb1,
    const float* __restrict__ cg,  const float* __restrict__ cB,
    const float* __restrict__ cW2, const float* __restrict__ cb2,
    const float* __restrict__ sW1, const float* __restrict__ sb1,
    const float* __restrict__ sg,  const float* __restrict__ sB,
    const float* __restrict__ sW2, const float* __restrict__ sb2,
    const float* __restrict__ mW1, const float* __restrict__ mb1,
    const float* __restrict__ mg,  const float* __restrict__ mB,
    const float* __restrict__ mW2, const float* __restrict__ mb2,
    const float* __restrict__ nW1, const float* __restrict__ nb1,
    const float* __restrict__ ng,  const float* __restrict__ nB,
    const float* __restrict__ nW2, const float* __restrict__ nb2,
    const float* __restrict__ tW1, const float* __restrict__ tb1,
    const float* __restrict__ tg,  const float* __restrict__ tB,
    const float* __restrict__ tW2, const float* __restrict__ tb2,
    const float* __restrict__ kW1, const float* __restrict__ kb1,
    const float* __restrict__ kg,  const float* __restrict__ kB,
    const float* __restrict__ kW2, const float* __restrict__ kb2,
    const float* __restrict__ pW1, const float* __restrict__ pb1,
    const float* __restrict__ pg,  const float* __restrict__ pB,
    const float* __restrict__ pW2, const float* __restrict__ pb2,
    float* __restrict__ h_ws, unsigned int* __restrict__ flagS,
    float* __restrict__ out)
{
    const int bid = blockIdx.x;
    const int t = threadIdx.x;

    // stage1 LDS
    __shared__ float u[170][20];
    __shared__ float h1[17][10][100];
    __shared__ float h2[17][100];
    __shared__ float spre[100][34];
    // stage2 LDS
    __shared__ float inrow[5][100];
    __shared__ float mnpart[4][2][20];
    __shared__ float hid4[4][20];
    __shared__ float v4[4][100];
    __shared__ float tpart[2][4][20];
    __shared__ float hidT[2][20];
    __shared__ float tv[2][100];
    __shared__ float kin[300];
    __shared__ float kpart[2][100];
    __shared__ float khid[100];
    __shared__ float comb[100];
    __shared__ float ppart[4][30];
    __shared__ float pact[30];
    __shared__ float red[8];

    if (bid < 14) {
        // ================= stage1: slice a =================
        const int a = bid;

        // Phase A: i lin1 + LN(20) + relu, one thread per row (b,c)
        if (t < 170) {
            const float* xr = x + (a*170 + t)*3;
            float x0 = xr[0], x1 = xr[1], x2 = xr[2];
            float pre[20];
            float mu = 0.f;
            #pragma unroll
            for (int j = 0; j < 20; ++j) {
                float v = ib1[j] + x0*iW1[j] + x1*iW1[20+j] + x2*iW1[40+j];
                pre[j] = v; mu += v;
            }
            mu *= 0.05f;
            float var = 0.f;
            #pragma unroll
            for (int j = 0; j < 20; ++j) { float d = pre[j]-mu; var = fmaf(d,d,var); }
            float inv = rsqrtf(var*0.05f + 1e-5f);
            #pragma unroll
            for (int j = 0; j < 20; ++j) {
                float v = (pre[j]-mu)*inv*ig[j] + iB[j];
                u[t][j] = v > 0.f ? v : 0.f;
            }
        }
        __syncthreads();

        // Phase B: i lin2, weights in regs, float4 LDS reads (500 threads)
        if (t < 500) {
            int d = t % 100, rg = t / 100;
            float w[20];
            #pragma unroll
            for (int j = 0; j < 20; ++j) w[j] = iW2[j*100+d];
            float bias = ib2[d];
            #pragma unroll 2
            for (int r = rg*34; r < rg*34+34; ++r) {
                const float4* ur = (const float4*)u[r];
                float4 u0=ur[0], u1=ur[1], u2=ur[2], u3=ur[3], u4=ur[4];
                float acc = bias;
                acc=fmaf(u0.x,w[0],acc);  acc=fmaf(u0.y,w[1],acc);
                acc=fmaf(u0.z,w[2],acc);  acc=fmaf(u0.w,w[3],acc);
                acc=fmaf(u1.x,w[4],acc);  acc=fmaf(u1.y,w[5],acc);
                acc=fmaf(u1.z,w[6],acc);  acc=fmaf(u1.w,w[7],acc);
                acc=fmaf(u2.x,w[8],acc);  acc=fmaf(u2.y,w[9],acc);
                acc=fmaf(u2.z,w[10],acc); acc=fmaf(u2.w,w[11],acc);
                acc=fmaf(u3.x,w[12],acc); acc=fmaf(u3.y,w[13],acc);
                acc=fmaf(u3.z,w[14],acc); acc=fmaf(u3.w,w[15],acc);
                acc=fmaf(u4.x,w[16],acc); acc=fmaf(u4.y,w[17],acc);
                acc=fmaf(u4.z,w[18],acc); acc=fmaf(u4.w,w[19],acc);
                ((float*)h1)[r*100+d] = acc;
            }
        }
        __syncthreads();

        // Phase C: stage c per (b,d)
        for (int o = t; o < 1700; o += T) {
            int b = o / 100, d = o - 100*b;
            float w[8];
            #pragma unroll
            for (int j = 0; j < 8; ++j) w[j] = cb1[j];
            #pragma unroll
            for (int c = 0; c < 10; ++c) {
                float v = h1[b][c][d];
                #pragma unroll
                for (int j = 0; j < 8; ++j) w[j] = fmaf(v, cW1[c*8+j], w[j]);
            }
            float mu = 0.f;
            #pragma unroll
            for (int j = 0; j < 8; ++j) mu += w[j];
            mu *= 0.125f;
            float var = 0.f;
            #pragma unroll
            for (int j = 0; j < 8; ++j) { float d2 = w[j]-mu; var = fmaf(d2,d2,var); }
            float inv = rsqrtf(var*0.125f + 1e-5f);
            float acc = cb2[0];
            #pragma unroll
            for (int j = 0; j < 8; ++j) {
                float v = (w[j]-mu)*inv*cg[j] + cB[j];
                v = v > 0.f ? v : 0.f;
                acc = fmaf(v, cW2[j], acc);
            }
            h2[b][d] = acc;
        }
        __syncthreads();

        // Phase D: s lin1 (d,j): 100x34, 17 MACs
        for (int o = t; o < 3400; o += T) {
            int d = o / 34, j = o - 34*d;
            float acc = sb1[j];
            #pragma unroll
            for (int b = 0; b < 17; ++b) acc = fmaf(h2[b][d], sW1[b*34+j], acc);
            spre[d][j] = acc;
        }
        __syncthreads();

        // Phase E: LN(34)+relu per d
        if (t < 100) {
            float mu = 0.f;
            #pragma unroll
            for (int j = 0; j < 34; ++j) mu += spre[t][j];
            mu *= (1.f/34.f);
            float var = 0.f;
            #pragma unroll
            for (int j = 0; j < 34; ++j) { float d = spre[t][j]-mu; var = fmaf(d,d,var); }
            float inv = rsqrtf(var*(1.f/34.f) + 1e-5f);
            #pragma unroll
            for (int j = 0; j < 34; ++j) {
                float v = (spre[t][j]-mu)*inv*sg[j] + sB[j];
                spre[t][j] = v > 0.f ? v : 0.f;
            }
        }
        __syncthreads();

        // Phase F: s lin2, transposed write h[a][b2][d]
        for (int o = t; o < 1700; o += T) {
            int d = o / 17, b2 = o - 17*d;
            float acc = sb2[b2];
            #pragma unroll
            for (int j = 0; j < 34; ++j) acc = fmaf(spre[d][j], sW2[j*17+b2], acc);
            h_ws[a*1700 + b2*100 + d] = acc;
        }
        __syncthreads();
        if (t == 0) {
            __builtin_amdgcn_fence(__ATOMIC_RELEASE, "agent");
            __hip_atomic_store(&flagS[a*32], 1u, __ATOMIC_RELAXED, __HIP_MEMORY_SCOPE_AGENT);
        }
        return;
    }

    // ================= stage2: task (f,b) =================
    const int task = bid - 14;
    const int f = task / 17, b = task % 17;
    const bool full = (f < 10);

    if (full) {
        // wave 0 polls the 14 padded flags, lanes 0..13 one each
        if (t < 64) {
            for (;;) {
                unsigned v = (t < 14)
                    ? __hip_atomic_load(&flagS[t*32], __ATOMIC_RELAXED, __HIP_MEMORY_SCOPE_AGENT)
                    : 1u;
                if (__all(v == 1u)) break;
                __builtin_amdgcn_s_sleep(8);
            }
        }
        __syncthreads();
        __builtin_amdgcn_fence(__ATOMIC_ACQUIRE, "agent");

        if (t < 100) {
            const float* hb = h_ws + b*100 + t;
            float h0  = hb[(f  )*1700];
            float h1v = hb[(f+1)*1700];
            float h2v = hb[(f+2)*1700];
            float h3v = hb[(f+3)*1700];
            float h4v = hb[(f+4)*1700];
            inrow[0][t] = h1v - h0;
            inrow[1][t] = h1v;
            inrow[2][t] = h4v - h3v;
            inrow[3][t] = h3v;
            inrow[4][t] = h2v;
        }
        __syncthreads();

        // m/n lin1, split-K x2
        if (t < 160) {
            int which = t / 40, rem = t % 40, half = rem / 20, jj = rem % 20;
            bool is_m = (which == 0) || (which == 2);
            const float* W1 = is_m ? mW1 : nW1;
            const float* in = inrow[which];
            int e0 = half*50;
            float a0 = 0.f, a1 = 0.f;
            #pragma unroll
            for (int e = 0; e < 50; e += 2) {
                a0 = fmaf(in[e0+e],   W1[(e0+e)*20+jj],   a0);
                a1 = fmaf(in[e0+e+1], W1[(e0+e+1)*20+jj], a1);
            }
            mnpart[which][half][jj] = a0 + a1;
        }
        __syncthreads();

        // combine + LN(20)+relu, waves 0..3
        {
            int w = t >> 6, lane = t & 63;
            bool act = (w < 4) && (lane < 20);
            bool is_m = (w == 0) || (w == 2);
            float v = 0.f;
            if (act) {
                const float* B1 = is_m ? mb1 : nb1;
                v = B1[lane] + mnpart[w][0][lane] + mnpart[w][1][lane];
            }
            float mu = wave_sum_all(v) * 0.05f;
            float dd = act ? (v-mu) : 0.f;
            float inv = rsqrtf(wave_sum_all(dd*dd)*0.05f + 1e-5f);
            if (act) {
                const float* g  = is_m ? mg : ng;
                const float* Bv = is_m ? mB : nB;
                float r = (v-mu)*inv*g[lane] + Bv[lane];
                hid4[w][lane] = r > 0.f ? r : 0.f;
            }
        }
        __syncthreads();

        // m/n lin2: 400 outputs x 20 MACs
        if (t < 400) {
            int which = t / 100, d = t % 100;
            bool is_m = (which == 0) || (which == 2);
            const float* W2 = is_m ? mW2 : nW2;
            const float* B2 = is_m ? mb2 : nb2;
            float acc = B2[d];
            #pragma unroll
            for (int j = 0; j < 20; ++j) acc = fmaf(hid4[which][j], W2[j*100+d], acc);
            v4[which][d] = acc;
        }
        __syncthreads();

        // t lin1, split-K x4. concat = [n_out, m_out]
        if (t < 160) {
            int jj = t % 20, q8 = t / 20;
            int which = q8 >> 2, q = q8 & 3;
            const float* inA = which ? v4[3] : v4[1];
            const float* inB = which ? v4[2] : v4[0];
            int e0 = q*50;
            const float* in = (q < 2) ? inA : inB;
            int inoff = (q < 2) ? e0 : e0 - 100;
            float a0 = 0.f, a1 = 0.f;
            #pragma unroll
            for (int e = 0; e < 50; e += 2) {
                a0 = fmaf(in[inoff+e],   tW1[(e0+e)*20+jj],   a0);
                a1 = fmaf(in[inoff+e+1], tW1[(e0+e+1)*20+jj], a1);
            }
            tpart[which][q][jj] = a0 + a1;
        }
        __syncthreads();

        // combine + LN(20)+relu, waves 0..1
        {
            int w = t >> 6, lane = t & 63;
            bool act = (w < 2) && (lane < 20);
            float v = 0.f;
            if (act)
                v = tb1[lane] + tpart[w][0][lane] + tpart[w][1][lane]
                              + tpart[w][2][lane] + tpart[w][3][lane];
            float mu = wave_sum_all(v) * 0.05f;
            float dd = act ? (v-mu) : 0.f;
            float inv = rsqrtf(wave_sum_all(dd*dd)*0.05f + 1e-5f);
            if (act) {
                float r = (v-mu)*inv*tg[lane] + tB[lane];
                hidT[w][lane] = r > 0.f ? r : 0.f;
            }
        }
        __syncthreads();

        // t lin2: 200 outputs x 20 MACs
        if (t < 200) {
            int which = t / 100, d = t % 100;
            float acc = tb2[d];
            #pragma unroll
            for (int j = 0; j < 20; ++j) acc = fmaf(hidT[which][j], tW2[j*100+d], acc);
            tv[which][d] = acc;
        }
        __syncthreads();

        // kin = concat [pf, hE, nf]
        if (t < 300)
            kin[t] = (t < 100) ? tv[0][t] : (t < 200 ? inrow[4][t-100] : tv[1][t-200]);
        __syncthreads();

        // k lin1, split-K x2: 200 threads x 150 MACs
        if (t < 200) {
            int o = t % 100, q = t / 100, e0 = q*150;
            float a0=0.f, a1=0.f, a2=0.f;
            #pragma unroll
            for (int e = 0; e < 150; e += 3) {
                a0 = fmaf(kin[e0+e],   kW1[(e0+e)*100+o],   a0);
                a1 = fmaf(kin[e0+e+1], kW1[(e0+e+1)*100+o], a1);
                a2 = fmaf(kin[e0+e+2], kW1[(e0+e+2)*100+o], a2);
            }
            kpart[q][o] = a0 + a1 + a2;
        }
        __syncthreads();

        // LN(100) block-wide (8 waves)
        {
            float kv = 0.f;
            if (t < 100) kv = kb1[t] + kpart[0][t] + kpart[1][t];
            float s = wave_sum_all((t < 100) ? kv : 0.f);
            if ((t & 63) == 0) red[t >> 6] = s;
            __syncthreads();
            float mu = (red[0]+red[1]+red[2]+red[3]+red[4]+red[5]+red[6]+red[7]) * 0.01f;
            __syncthreads();
            float dd = (t < 100) ? (kv-mu) : 0.f;
            float s2 = wave_sum_all(dd*dd);
            if ((t & 63) == 0) red[t >> 6] = s2;
            __syncthreads();
            float var = (red[0]+red[1]+red[2]+red[3]+red[4]+red[5]+red[6]+red[7]) * 0.01f;
            float inv = rsqrtf(var + 1e-5f);
            if (t < 100) {
                float r = (kv-mu)*inv*kg[t] + kB[t];
                khid[t] = r > 0.f ? r : 0.f;
            }
        }
        __syncthreads();

        // k lin2: 100 outputs x 100 MACs
        if (t < 100) {
            float a0=0.f,a1=0.f,a2=0.f,a3=0.f;
            for (int j = 0; j < 100; j += 4) {
                a0 = fmaf(khid[j+0], kW2[(j+0)*100+t], a0);
                a1 = fmaf(khid[j+1], kW2[(j+1)*100+t], a1);
                a2 = fmaf(khid[j+2], kW2[(j+2)*100+t], a2);
                a3 = fmaf(khid[j+3], kW2[(j+3)*100+t], a3);
            }
            comb[t] = kb2[t] + ((a0+a1)+(a2+a3));
        }
        __syncthreads();
    } else {
        if (t < 100) comb[t] = 0.f;
        __syncthreads();
    }

    // p stage: 100 -> 30 (LN) -> 3, lin1 split-K x4
    if (t < 120) {
        int o = t % 30, q = t / 30, e0 = q*25;
        float a0 = 0.f;
        #pragma unroll
        for (int e = 0; e < 25; ++e)
            a0 = fmaf(comb[e0+e], pW1[(e0+e)*30+o], a0);
        ppart[q][o] = a0;
    }
    __syncthreads();
    if (t < 64) {
        float v = 0.f;
        if (t < 30) v = pb1[t] + ppart[0][t] + ppart[1][t] + ppart[2][t] + ppart[3][t];
        float mu = wave_sum_all(v) * (1.f/30.f);
        float dd = (t < 30) ? (v-mu) : 0.f;
        float inv = rsqrtf(wave_sum_all(dd*dd)*(1.f/30.f) + 1e-5f);
        if (t < 30) {
            float r = (v-mu)*inv*pg[t] + pB[t];
            pact[t] = r > 0.f ? r : 0.f;
        }
    }
    __syncthreads();
    if (t < 3) {
        float acc = pb2[t];
        #pragma unroll
        for (int j = 0; j < 30; ++j) acc = fmaf(pact[j], pW2[j*3+t], acc);
        out[(f*17 + b)*3 + t] = acc;
    }
}

extern "C" void kernel_launch(void* const* d_in, const int* in_sizes, int n_in,
                              void* d_out, int out_size, void* d_ws, size_t ws_size,
                              hipStream_t stream) {
    const float* x = (const float*)d_in[0];
    float* h = (float*)d_ws;                                  // [14][17][100]
    unsigned int* flags = (unsigned int*)((char*)d_ws + FLAG_BYTE);
    hipMemsetAsync(flags, 0, 14*128, stream);                 // 14 padded flags
    #define P(i) ((const float*)d_in[i])
    k_fused<<<218, T, 0, stream>>>(x,
        P(1), P(2), P(3), P(4), P(5), P(6),
        P(7), P(8), P(9), P(10), P(11), P(12),
        P(13), P(14), P(15), P(16), P(17), P(18),
        P(19), P(20), P(21), P(22), P(23), P(24),
        P(25), P(26), P(27), P(28), P(29), P(30),
        P(31), P(32), P(33), P(34), P(35), P(36),
        P(37), P(38), P(39), P(40), P(41), P(42),
        P(43), P(44), P(45), P(46), P(47), P(48),
        h, flags, (float*)d_out);
    #undef P
}

// Round 5
// 38.734 us; speedup vs baseline: 1.6276x; 1.3004x over previous
//
#include <hip/hip_runtime.h>

#define T 512
#define NS1 70                 // stage1 blocks: (a=bid/5, dgroup=bid%5)
#define ZBLK 240               // zero-row block
#define FLAG_BYTE 98304        // flags offset in ws (after h[23800] floats)

__device__ __forceinline__ float wave_sum_all(float v){
    #pragma unroll
    for (int off = 1; off < 64; off <<= 1) v += __shfl_xor(v, off, 64);
    return v;
}

struct S1 {
    float u[170][20];
    float h2s[17][20];
    float spre[20][34];
    float iW1[60], ib1[20], ig[20], iB[20], iW2[2000], ib2[100];
    float cW1[80], cb1[8], cg[8], cB[8], cW2[8], cb2s[1];
    float sW1[578], sb1[34], sg[34], sB[34], sW2[578], sb2[17];
};
struct S2 {
    float inrow[4][100];       // dA, hA, dC, hD
    float mnpart[4][20][2];
    float v4[4][100];
    float tpart[2][20][4];
    float kin[300];            // [tv0 | hE | tv1] contiguous
    float kpart[5][100];
    float khid[100];
    float comb[100];
    float ppart[4][30];
    float mW1[2000], mb1[20], mg[20], mB[20], mW2[2000], mb2[100];
    float nW1[2000], nb1[20], ng[20], nB[20], nW2[2000], nb2[100];
    float tW1[4000], tb1[20], tg[20], tB[20], tW2[2000], tb2[100];
    float kb1[100], kg[100], kB[100], kW2[10000], kb2[100];
    float pW1[3000], pb1[30], pg[30], pB[30], pW2[90], pb2[3];
};
union SMem { S1 s1; S2 s2; };

__device__ __forceinline__ void cp(float* dst, const float* src, int n, int t){
    for (int i = t; i < n; i += T) dst[i] = src[i];
}

__global__ __launch_bounds__(T) void k_fused(
    const float* __restrict__ x,
    const float* __restrict__ iW1, const float* __restrict__ ib1,
    const float* __restrict__ ig,  const float* __restrict__ iB,
    const float* __restrict__ iW2, const float* __restrict__ ib2,
    const float* __restrict__ cW1, const float* __restrict__ cb1,
    const float* __restrict__ cg,  const float* __restrict__ cB,
    const float* __restrict__ cW2, const float* __restrict__ cb2,
    const float* __restrict__ sW1, const float* __restrict__ sb1,
    const float* __restrict__ sg,  const float* __restrict__ sB,
    const float* __restrict__ sW2, const float* __restrict__ sb2,
    const float* __restrict__ mW1, const float* __restrict__ mb1,
    const float* __restrict__ mg,  const float* __restrict__ mB,
    const float* __restrict__ mW2, const float* __restrict__ mb2,
    const float* __restrict__ nW1, const float* __restrict__ nb1,
    const float* __restrict__ ng,  const float* __restrict__ nB,
    const float* __restrict__ nW2, const float* __restrict__ nb2,
    const float* __restrict__ tW1, const float* __restrict__ tb1,
    const float* __restrict__ tg,  const float* __restrict__ tB,
    const float* __restrict__ tW2, const float* __restrict__ tb2,
    const float* __restrict__ kW1, const float* __restrict__ kb1,
    const float* __restrict__ kg,  const float* __restrict__ kB,
    const float* __restrict__ kW2, const float* __restrict__ kb2,
    const float* __restrict__ pW1, const float* __restrict__ pb1,
    const float* __restrict__ pg,  const float* __restrict__ pB,
    const float* __restrict__ pW2, const float* __restrict__ pb2,
    float* __restrict__ h_ws, unsigned int* __restrict__ flagS,
    float* __restrict__ out)
{
    const int bid = blockIdx.x;
    const int t = threadIdx.x;
    __shared__ SMem sm;

    if (bid < NS1) {
        // ============== stage1: (a, dgroup) slice, i -> c -> s ==============
        S1& s = sm.s1;
        cp(s.iW1, iW1, 60, t);  cp(s.ib1, ib1, 20, t);  cp(s.ig, ig, 20, t);
        cp(s.iB, iB, 20, t);    cp(s.iW2, iW2, 2000, t); cp(s.ib2, ib2, 100, t);
        cp(s.cW1, cW1, 80, t);  cp(s.cb1, cb1, 8, t);   cp(s.cg, cg, 8, t);
        cp(s.cB, cB, 8, t);     cp(s.cW2, cW2, 8, t);   cp(s.cb2s, cb2, 1, t);
        cp(s.sW1, sW1, 578, t); cp(s.sb1, sb1, 34, t);  cp(s.sg, sg, 34, t);
        cp(s.sB, sB, 34, t);    cp(s.sW2, sW2, 578, t); cp(s.sb2, sb2, 17, t);
        __syncthreads();

        const int a = bid / 5, d0 = (bid % 5) * 20;

        // A: i lin1 + LN(20) + relu (full u, redundant across dgroups — tiny)
        if (t < 170) {
            const float* xr = x + (a*170 + t)*3;
            float x0 = xr[0], x1 = xr[1], x2 = xr[2];
            float pre[20];
            float mu = 0.f;
            #pragma unroll
            for (int j = 0; j < 20; ++j) {
                float v = s.ib1[j] + x0*s.iW1[j] + x1*s.iW1[20+j] + x2*s.iW1[40+j];
                pre[j] = v; mu += v;
            }
            mu *= 0.05f;
            float var = 0.f;
            #pragma unroll
            for (int j = 0; j < 20; ++j) { float d = pre[j]-mu; var = fmaf(d,d,var); }
            float inv = rsqrtf(var*0.05f + 1e-5f);
            #pragma unroll
            for (int j = 0; j < 20; ++j) {
                float v = (pre[j]-mu)*inv*s.ig[j] + s.iB[j];
                s.u[t][j] = v > 0.f ? v : 0.f;
            }
        }
        __syncthreads();

        // BC fused: i lin2 + stage c, per (b, dd): 340 outputs
        if (t < 340) {
            int b = t / 20, dd = t % 20, d = d0 + dd;
            float w[8];
            #pragma unroll
            for (int j = 0; j < 8; ++j) w[j] = s.cb1[j];
            float bias = s.ib2[d];
            #pragma unroll 2
            for (int c = 0; c < 10; ++c) {
                const float4* ur = (const float4*)s.u[b*10 + c];
                float4 u0=ur[0], u1=ur[1], u2=ur[2], u3=ur[3], u4=ur[4];
                float acc = bias;
                acc=fmaf(u0.x,s.iW2[0*100+d],acc);  acc=fmaf(u0.y,s.iW2[1*100+d],acc);
                acc=fmaf(u0.z,s.iW2[2*100+d],acc);  acc=fmaf(u0.w,s.iW2[3*100+d],acc);
                acc=fmaf(u1.x,s.iW2[4*100+d],acc);  acc=fmaf(u1.y,s.iW2[5*100+d],acc);
                acc=fmaf(u1.z,s.iW2[6*100+d],acc);  acc=fmaf(u1.w,s.iW2[7*100+d],acc);
                acc=fmaf(u2.x,s.iW2[8*100+d],acc);  acc=fmaf(u2.y,s.iW2[9*100+d],acc);
                acc=fmaf(u2.z,s.iW2[10*100+d],acc); acc=fmaf(u2.w,s.iW2[11*100+d],acc);
                acc=fmaf(u3.x,s.iW2[12*100+d],acc); acc=fmaf(u3.y,s.iW2[13*100+d],acc);
                acc=fmaf(u3.z,s.iW2[14*100+d],acc); acc=fmaf(u3.w,s.iW2[15*100+d],acc);
                acc=fmaf(u4.x,s.iW2[16*100+d],acc); acc=fmaf(u4.y,s.iW2[17*100+d],acc);
                acc=fmaf(u4.z,s.iW2[18*100+d],acc); acc=fmaf(u4.w,s.iW2[19*100+d],acc);
                #pragma unroll
                for (int j = 0; j < 8; ++j) w[j] = fmaf(acc, s.cW1[c*8+j], w[j]);
            }
            float mu = 0.f;
            #pragma unroll
            for (int j = 0; j < 8; ++j) mu += w[j];
            mu *= 0.125f;
            float var = 0.f;
            #pragma unroll
            for (int j = 0; j < 8; ++j) { float d2 = w[j]-mu; var = fmaf(d2,d2,var); }
            float inv = rsqrtf(var*0.125f + 1e-5f);
            float acc = s.cb2s[0];
            #pragma unroll
            for (int j = 0; j < 8; ++j) {
                float v = (w[j]-mu)*inv*s.cg[j] + s.cB[j];
                v = v > 0.f ? v : 0.f;
                acc = fmaf(v, s.cW2[j], acc);
            }
            s.h2s[b][dd] = acc;
        }
        __syncthreads();

        // D: s lin1: (dd, j) 20x34, 17 MACs
        for (int o = t; o < 680; o += T) {
            int dd = o / 34, j = o % 34;
            float acc = s.sb1[j];
            #pragma unroll
            for (int b = 0; b < 17; ++b) acc = fmaf(s.h2s[b][dd], s.sW1[b*34+j], acc);
            s.spre[dd][j] = acc;
        }
        __syncthreads();

        // E: LN(34)+relu per dd
        if (t < 20) {
            float mu = 0.f;
            #pragma unroll
            for (int j = 0; j < 34; ++j) mu += s.spre[t][j];
            mu *= (1.f/34.f);
            float var = 0.f;
            #pragma unroll
            for (int j = 0; j < 34; ++j) { float d = s.spre[t][j]-mu; var = fmaf(d,d,var); }
            float inv = rsqrtf(var*(1.f/34.f) + 1e-5f);
            #pragma unroll
            for (int j = 0; j < 34; ++j) {
                float v = (s.spre[t][j]-mu)*inv*s.sg[j] + s.sB[j];
                s.spre[t][j] = v > 0.f ? v : 0.f;
            }
        }
        __syncthreads();

        // F: s lin2, transposed write h[a][b2][d0+dd]
        if (t < 340) {
            int dd = t / 17, b2 = t % 17;
            float acc = s.sb2[b2];
            #pragma unroll
            for (int j = 0; j < 34; ++j) acc = fmaf(s.spre[dd][j], s.sW2[j*17+b2], acc);
            h_ws[a*1700 + b2*100 + d0 + dd] = acc;
        }
        __syncthreads();
        if (t == 0) {
            __builtin_amdgcn_fence(__ATOMIC_RELEASE, "agent");
            __hip_atomic_store(&flagS[bid*32], 1u, __ATOMIC_RELAXED, __HIP_MEMORY_SCOPE_AGENT);
        }
        return;
    }

    // ============== stage2 ==============
    S2& s = sm.s2;
    cp(s.mW1, mW1, 2000, t); cp(s.mb1, mb1, 20, t); cp(s.mg, mg, 20, t);
    cp(s.mB, mB, 20, t);     cp(s.mW2, mW2, 2000, t); cp(s.mb2, mb2, 100, t);
    cp(s.nW1, nW1, 2000, t); cp(s.nb1, nb1, 20, t); cp(s.ng, ng, 20, t);
    cp(s.nB, nB, 20, t);     cp(s.nW2, nW2, 2000, t); cp(s.nb2, nb2, 100, t);
    cp(s.tW1, tW1, 4000, t); cp(s.tb1, tb1, 20, t); cp(s.tg, tg, 20, t);
    cp(s.tB, tB, 20, t);     cp(s.tW2, tW2, 2000, t); cp(s.tb2, tb2, 100, t);
    cp(s.kb1, kb1, 100, t);  cp(s.kg, kg, 100, t);  cp(s.kB, kB, 100, t);
    cp(s.kW2, kW2, 10000, t); cp(s.kb2, kb2, 100, t);
    cp(s.pW1, pW1, 3000, t); cp(s.pb1, pb1, 30, t); cp(s.pg, pg, 30, t);
    cp(s.pB, pB, 30, t);     cp(s.pW2, pW2, 90, t); cp(s.pb2, pb2, 3, t);

    const int task = bid - NS1;
    const int kq = t / 100, ko = t % 100;
    float wk[60];
    if (bid != ZBLK) {
        if (t < 500) {
            #pragma unroll
            for (int e = 0; e < 60; ++e) wk[e] = kW1[(kq*60+e)*100 + ko];
        }
        // spin: wave0 polls the 70 padded flags (read-only relaxed)
        if (t < 64) {
            for (;;) {
                unsigned v1 = __hip_atomic_load(&flagS[t*32], __ATOMIC_RELAXED, __HIP_MEMORY_SCOPE_AGENT);
                unsigned v2 = (t < 6)
                    ? __hip_atomic_load(&flagS[(64+t)*32], __ATOMIC_RELAXED, __HIP_MEMORY_SCOPE_AGENT)
                    : 1u;
                if (__all(v1 && v2)) break;
                __builtin_amdgcn_s_sleep(2);
            }
        }
    }
    __syncthreads();
    __builtin_amdgcn_fence(__ATOMIC_ACQUIRE, "agent");

    if (bid != ZBLK) {
        const int f = task / 17, b = task % 17;

        // 1: load h rows -> inrow + hE
        if (t < 100) {
            const float* hb = h_ws + b*100 + t;
            float h0  = hb[(f  )*1700];
            float h1v = hb[(f+1)*1700];
            float h2v = hb[(f+2)*1700];
            float h3v = hb[(f+3)*1700];
            float h4v = hb[(f+4)*1700];
            s.inrow[0][t] = h1v - h0;
            s.inrow[1][t] = h1v;
            s.inrow[2][t] = h4v - h3v;
            s.inrow[3][t] = h3v;
            s.kin[100+t]  = h2v;          // hE
        }
        __syncthreads();

        // 2: m/n lin1 partials (split-K x2)
        if (t < 160) {
            int which = t / 40, rem = t % 40, half = rem / 20, jj = rem % 20;
            const float* W1 = (which & 1) ? s.nW1 : s.mW1;
            const float* in = s.inrow[which];
            int e0 = half*50;
            float a0 = 0.f, a1 = 0.f;
            #pragma unroll
            for (int e = 0; e < 50; e += 2) {
                a0 = fmaf(in[e0+e],   W1[(e0+e)*20+jj],   a0);
                a1 = fmaf(in[e0+e+1], W1[(e0+e+1)*20+jj], a1);
            }
            s.mnpart[which][jj][half] = a0 + a1;
        }
        __syncthreads();

        // 3: m/n lin2 with folded LN(20)+relu
        if (t < 400) {
            int which = t / 100, d = t % 100;
            bool is_m = !(which & 1);
            const float* b1 = is_m ? s.mb1 : s.nb1;
            const float* g  = is_m ? s.mg  : s.ng;
            const float* Bv = is_m ? s.mB  : s.nB;
            const float* W2 = is_m ? s.mW2 : s.nW2;
            const float* b2 = is_m ? s.mb2 : s.nb2;
            float pre[20];
            float mu = 0.f;
            #pragma unroll
            for (int j = 0; j < 20; ++j) {
                float2 mp = *(const float2*)s.mnpart[which][j];
                pre[j] = b1[j] + mp.x + mp.y; mu += pre[j];
            }
            mu *= 0.05f;
            float var = 0.f;
            #pragma unroll
            for (int j = 0; j < 20; ++j) { float dd2 = pre[j]-mu; var = fmaf(dd2,dd2,var); }
            float inv = rsqrtf(var*0.05f + 1e-5f);
            float acc = b2[d];
            #pragma unroll
            for (int j = 0; j < 20; ++j) {
                float h = (pre[j]-mu)*inv*g[j] + Bv[j];
                h = h > 0.f ? h : 0.f;
                acc = fmaf(h, W2[j*100+d], acc);
            }
            s.v4[which][d] = acc;
        }
        __syncthreads();

        // 4: t lin1 partials (split-K x4), concat = [n_out, m_out]
        if (t < 160) {
            int jj = t % 20, q8 = t / 20;
            int which = q8 >> 2, q = q8 & 3;
            int e0 = q*50;
            const float* src = (q < 2) ? s.v4[which ? 3 : 1] : s.v4[which ? 2 : 0];
            int off = (q < 2) ? e0 : e0 - 100;
            float a0 = 0.f, a1 = 0.f;
            #pragma unroll
            for (int e = 0; e < 50; e += 2) {
                a0 = fmaf(src[off+e],   s.tW1[(e0+e)*20+jj],   a0);
                a1 = fmaf(src[off+e+1], s.tW1[(e0+e+1)*20+jj], a1);
            }
            s.tpart[which][jj][q] = a0 + a1;
        }
        __syncthreads();

        // 5: t lin2 with folded LN(20)+relu -> kin[0..99]=pf, kin[200..299]=nf
        if (t < 200) {
            int which = t / 100, d = t % 100;
            float pre[20];
            float mu = 0.f;
            #pragma unroll
            for (int j = 0; j < 20; ++j) {
                float4 tp = *(const float4*)s.tpart[which][j];
                pre[j] = s.tb1[j] + ((tp.x+tp.y)+(tp.z+tp.w)); mu += pre[j];
            }
            mu *= 0.05f;
            float var = 0.f;
            #pragma unroll
            for (int j = 0; j < 20; ++j) { float dd2 = pre[j]-mu; var = fmaf(dd2,dd2,var); }
            float inv = rsqrtf(var*0.05f + 1e-5f);
            float acc = s.tb2[d];
            #pragma unroll
            for (int j = 0; j < 20; ++j) {
                float h = (pre[j]-mu)*inv*s.tg[j] + s.tB[j];
                h = h > 0.f ? h : 0.f;
                acc = fmaf(h, s.tW2[j*100+d], acc);
            }
            s.kin[which*200 + d] = acc;
        }
        __syncthreads();

        // 6: k lin1 partials from register weights (split-K x5)
        if (t < 500) {
            const float* base = s.kin + kq*60;
            float a0=0.f, a1=0.f, a2=0.f;
            #pragma unroll
            for (int e = 0; e < 60; e += 3) {
                a0 = fmaf(base[e],   wk[e],   a0);
                a1 = fmaf(base[e+1], wk[e+1], a1);
                a2 = fmaf(base[e+2], wk[e+2], a2);
            }
            s.kpart[kq][ko] = a0 + a1 + a2;
        }
        __syncthreads();

        // 7: LN(100)+relu on wave0 via lane folding (lane l handles l and 64+l)
        if (t < 64) {
            int l = t;
            float kv1 = s.kb1[l];
            #pragma unroll
            for (int q = 0; q < 5; ++q) kv1 += s.kpart[q][l];
            bool h36 = (l < 36);
            float kv2 = 0.f;
            if (h36) {
                kv2 = s.kb1[64+l];
                #pragma unroll
                for (int q = 0; q < 5; ++q) kv2 += s.kpart[q][64+l];
            }
            float mu = wave_sum_all(kv1 + (h36 ? kv2 : 0.f)) * 0.01f;
            float d1 = kv1 - mu, d2 = h36 ? kv2 - mu : 0.f;
            float var = wave_sum_all(fmaf(d1,d1,d2*d2)) * 0.01f;
            float inv = rsqrtf(var + 1e-5f);
            float r1 = d1*inv*s.kg[l] + s.kB[l];
            s.khid[l] = r1 > 0.f ? r1 : 0.f;
            if (h36) {
                float r2 = d2*inv*s.kg[64+l] + s.kB[64+l];
                s.khid[64+l] = r2 > 0.f ? r2 : 0.f;
            }
        }
        __syncthreads();

        // 8: k lin2 -> comb
        if (t < 100) {
            float a0=0.f,a1=0.f,a2=0.f,a3=0.f;
            for (int j = 0; j < 100; j += 4) {
                a0 = fmaf(s.khid[j+0], s.kW2[(j+0)*100+t], a0);
                a1 = fmaf(s.khid[j+1], s.kW2[(j+1)*100+t], a1);
                a2 = fmaf(s.khid[j+2], s.kW2[(j+2)*100+t], a2);
                a3 = fmaf(s.khid[j+3], s.kW2[(j+3)*100+t], a3);
            }
            s.comb[t] = s.kb2[t] + ((a0+a1)+(a2+a3));
        }
        __syncthreads();

        // 9: p lin1 partials (split-K x4)
        if (t < 120) {
            int o = t % 30, q = t / 30, e0 = q*25;
            float a0 = 0.f;
            #pragma unroll
            for (int e = 0; e < 25; ++e)
                a0 = fmaf(s.comb[e0+e], s.pW1[(e0+e)*30+o], a0);
            s.ppart[q][o] = a0;
        }
        __syncthreads();

        // 10: LN(30)+relu + p lin2 as wave reduction + store
        if (t < 64) {
            int l = t;
            float v = 0.f;
            if (l < 30)
                v = s.pb1[l] + s.ppart[0][l] + s.ppart[1][l] + s.ppart[2][l] + s.ppart[3][l];
            float mu = wave_sum_all(v) * (1.f/30.f);
            float dd2 = (l < 30) ? v - mu : 0.f;
            float inv = rsqrtf(wave_sum_all(dd2*dd2)*(1.f/30.f) + 1e-5f);
            float pa = 0.f;
            if (l < 30) {
                pa = dd2*inv*s.pg[l] + s.pB[l];
                pa = pa > 0.f ? pa : 0.f;
            }
            float o0 = wave_sum_all((l < 30) ? pa*s.pW2[l*3+0] : 0.f);
            float o1 = wave_sum_all((l < 30) ? pa*s.pW2[l*3+1] : 0.f);
            float o2 = wave_sum_all((l < 30) ? pa*s.pW2[l*3+2] : 0.f);
            if (t == 0) {
                int r = f*17 + b;
                out[r*3+0] = s.pb2[0] + o0;
                out[r*3+1] = s.pb2[1] + o1;
                out[r*3+2] = s.pb2[2] + o2;
            }
        }
    } else {
        // zero block: p-MLP on zero input, broadcast to rows 170..203 (f=10,11)
        if (t < 64) {
            int l = t;
            float v = (l < 30) ? s.pb1[l] : 0.f;
            float mu = wave_sum_all(v) * (1.f/30.f);
            float dd2 = (l < 30) ? v - mu : 0.f;
            float inv = rsqrtf(wave_sum_all(dd2*dd2)*(1.f/30.f) + 1e-5f);
            float pa = 0.f;
            if (l < 30) {
                pa = dd2*inv*s.pg[l] + s.pB[l];
                pa = pa > 0.f ? pa : 0.f;
            }
            float o0 = s.pb2[0] + wave_sum_all((l < 30) ? pa*s.pW2[l*3+0] : 0.f);
            float o1 = s.pb2[1] + wave_sum_all((l < 30) ? pa*s.pW2[l*3+1] : 0.f);
            float o2 = s.pb2[2] + wave_sum_all((l < 30) ? pa*s.pW2[l*3+2] : 0.f);
            if (l < 34) {
                int r = 170 + l;
                out[r*3+0] = o0; out[r*3+1] = o1; out[r*3+2] = o2;
            }
        }
    }
}

extern "C" void kernel_launch(void* const* d_in, const int* in_sizes, int n_in,
                              void* d_out, int out_size, void* d_ws, size_t ws_size,
                              hipStream_t stream) {
    const float* x = (const float*)d_in[0];
    float* h = (float*)d_ws;                                  // [14][17][100]
    unsigned int* flags = (unsigned int*)((char*)d_ws + FLAG_BYTE);
    hipMemsetAsync(flags, 0, NS1*128, stream);                // 70 padded flags
    #define P(i) ((const float*)d_in[i])
    k_fused<<<241, T, 0, stream>>>(x,
        P(1), P(2), P(3), P(4), P(5), P(6),
        P(7), P(8), P(9), P(10), P(11), P(12),
        P(13), P(14), P(15), P(16), P(17), P(18),
        P(19), P(20), P(21), P(22), P(23), P(24),
        P(25), P(26), P(27), P(28), P(29), P(30),
        P(31), P(32), P(33), P(34), P(35), P(36),
        P(37), P(38), P(39), P(40), P(41), P(42),
        P(43), P(44), P(45), P(46), P(47), P(48),
        h, flags, (float*)d_out);
    #undef P
}